// Round 5
// baseline (271.781 us; speedup 1.0000x reference)
//
#include <hip/hip_runtime.h>
#include <hip/hip_bf16.h>

// Problem constants
#define B_  2
#define N_  2048
#define D_  1024
#define H_  16
#define DH_ 64
#define BN_ (B_*N_)   // 4096 rows total

typedef __attribute__((ext_vector_type(8))) short short8;  // 8 bf16 = 4 VGPRs (MFMA A/B frag)
typedef __attribute__((ext_vector_type(4))) float f32x4;   // MFMA C/D frag

typedef __attribute__((address_space(3))) unsigned int lds_u32_t;
typedef const __attribute__((address_space(1))) unsigned int glb_u32_t;

// async global->LDS, 16B per lane; LDS dst = (wave-uniform base) + lane*16
__device__ __forceinline__ void async_load16(const unsigned short* g, unsigned short* l) {
    __builtin_amdgcn_global_load_lds((glb_u32_t*)g, (lds_u32_t*)l, 16, 0, 0);
}

__device__ __forceinline__ unsigned short f2bf(float f) {
    __hip_bfloat16 h = __float2bfloat16(f);
    return *reinterpret_cast<unsigned short*>(&h);
}

// pack bf16(a) into low16, bf16(b) into high16; round-half-up via +0x8000,
// then one v_perm_b32 grabs the two high halves.
__device__ __forceinline__ unsigned int pkbf(float a, float b) {
    unsigned int ua = __float_as_uint(a) + 0x8000u;
    unsigned int ub = __float_as_uint(b) + 0x8000u;
    return __builtin_amdgcn_perm(ub, ua, 0x07060302);
}

// softmax scale folded into Q projection: 1/sqrt(DH) * log2(e)
#define QSCL 0.1803368801111204f

// ---------------------------------------------------------------------------
// Kernel 1: cast fp32 -> bf16 for x, Wq, Wk, Wv, Wo (one fused launch)
// ---------------------------------------------------------------------------
__global__ __launch_bounds__(256) void cast_kernel(
    const float* __restrict__ x,  const float* __restrict__ wq,
    const float* __restrict__ wk, const float* __restrict__ wv,
    const float* __restrict__ wo,
    unsigned short* __restrict__ xb,  unsigned short* __restrict__ wqb,
    unsigned short* __restrict__ wkb, unsigned short* __restrict__ wvb,
    unsigned short* __restrict__ wob)
{
    const size_t NX = (size_t)BN_ * D_;   // 4194304
    const size_t NW = (size_t)D_ * D_;    // 1048576 (pow2)
    size_t i = ((size_t)blockIdx.x * 256 + threadIdx.x) * 4;
    const float* src; unsigned short* dst; size_t off;
    if (i < NX) { src = x; dst = xb; off = i; }
    else {
        size_t j = (i - NX) >> 20;          // which W
        off = (i - NX) & (NW - 1);
        src = (j == 0) ? wq : (j == 1) ? wk : (j == 2) ? wv : wo;
        dst = (j == 0) ? wqb : (j == 1) ? wkb : (j == 2) ? wvb : wob;
    }
    float4 v = *(const float4*)(src + off);
    ushort4 o;
    o.x = f2bf(v.x); o.y = f2bf(v.y); o.z = f2bf(v.z); o.w = f2bf(v.w);
    *(ushort4*)(dst + off) = o;
}

// ---------------------------------------------------------------------------
// GEMM body: C[M,Nc] = A[M,K](bf16) @ W[Nc,K]^T(bf16) + bias
// 128x128 tile, BK=64, 4 waves (2x2 of 64x64), 16x16x32 bf16 MFMA.
// Staging: global_load_lds width=16, unpadded 128B rows, fetch-side XOR
// swizzle (16B block ^ (row&7)) -> frag b128 reads are 2-way (free).
// OUT_MODE: 0 = f32 row-major, 1 = bf16 row-major, 2 = bf16 TRANSPOSED (V^T),
//           3 = bf16 row-major scaled by QSCL (Q projection)
// ---------------------------------------------------------------------------
template<int OUT_MODE>
__device__ __forceinline__ void gemm_body(
    const unsigned short* __restrict__ A, const unsigned short* __restrict__ W,
    const float* __restrict__ bias, void* __restrict__ Cout, int bx, int by)
{
    constexpr int K = D_;
    __shared__ __align__(16) unsigned short As[128 * 64];   // 16 KB
    __shared__ __align__(16) unsigned short Bs[128 * 64];   // 16 KB
    const int tid  = threadIdx.x;
    const int lane = tid & 63;
    const int wave = tid >> 6;
    const int wm = wave & 1, wn = wave >> 1;
    const int l15 = lane & 15, quad = lane >> 4;

    f32x4 acc[4][4] = {};
    const int row0 = by * 128, col0 = bx * 128;

    const int srow = lane >> 3;   // row within 1KB chunk (8 rows x 128B)
    const int scb  = lane & 7;    // 16B block within row

    for (int k0 = 0; k0 < K; k0 += 64) {
        __syncthreads();          // prev iteration's frag reads done
#pragma unroll
        for (int cc = 0; cc < 4; ++cc) {       // 16 chunks / 4 waves
            int c  = wave * 4 + cc;
            int lr = c * 8 + srow;             // tile row 0..127
            int gcol = k0 + ((scb ^ (lr & 7)) * 8);
            async_load16(A + (size_t)(row0 + lr) * K + gcol, (unsigned short*)As + c * 512);
            async_load16(W + (size_t)(col0 + lr) * K + gcol, (unsigned short*)Bs + c * 512);
        }
        __syncthreads();          // staging complete (vmcnt drained at barrier)

#pragma unroll
        for (int kf = 0; kf < 2; ++kf) {
            const int swz = ((kf * 4 + quad) ^ (l15 & 7)) * 8;
            short8 af[4], bf[4];
#pragma unroll
            for (int mi = 0; mi < 4; mi++)
                af[mi] = *(const short8*)(&As[(wm * 64 + mi * 16 + l15) * 64 + swz]);
#pragma unroll
            for (int ni = 0; ni < 4; ni++)
                bf[ni] = *(const short8*)(&Bs[(wn * 64 + ni * 16 + l15) * 64 + swz]);
#pragma unroll
            for (int mi = 0; mi < 4; mi++)
#pragma unroll
                for (int ni = 0; ni < 4; ni++)
                    acc[mi][ni] = __builtin_amdgcn_mfma_f32_16x16x32_bf16(
                        af[mi], bf[ni], acc[mi][ni], 0, 0, 0);
        }
    }

#pragma unroll
    for (int ni = 0; ni < 4; ni++) {
        int col = col0 + wn * 64 + ni * 16 + l15;
        float bv = bias[col];
#pragma unroll
        for (int mi = 0; mi < 4; mi++) {
            int row = row0 + wm * 64 + mi * 16 + quad * 4;
            if (OUT_MODE == 2) {
                // V^T store: vt[col][row], 4 adjacent rows pack to one 8B store
                ushort4 pk;
                pk.x = f2bf(acc[mi][ni][0] + bv);
                pk.y = f2bf(acc[mi][ni][1] + bv);
                pk.z = f2bf(acc[mi][ni][2] + bv);
                pk.w = f2bf(acc[mi][ni][3] + bv);
                *(ushort4*)((unsigned short*)Cout + (size_t)col * BN_ + row) = pk;
            } else {
#pragma unroll
                for (int r = 0; r < 4; r++) {
                    float v = acc[mi][ni][r] + bv;
                    if (OUT_MODE == 3) v *= QSCL;
                    if (OUT_MODE == 0)
                        ((float*)Cout)[(size_t)(row + r) * D_ + col] = v;
                    else
                        ((unsigned short*)Cout)[(size_t)(row + r) * D_ + col] = f2bf(v);
                }
            }
        }
    }
}

// Kernel 2: fused QKV projection (z selects q/k/v; q pre-scaled, v transposed)
__global__ __launch_bounds__(256) void qkv_gemm(
    const unsigned short* __restrict__ xb,
    const unsigned short* __restrict__ wqb, const unsigned short* __restrict__ wkb,
    const unsigned short* __restrict__ wvb,
    const float* __restrict__ bq, const float* __restrict__ bk, const float* __restrict__ bv,
    unsigned short* __restrict__ q, unsigned short* __restrict__ k, unsigned short* __restrict__ vt)
{
    if (blockIdx.z == 0)
        gemm_body<3>(xb, wqb, bq, q,  blockIdx.x, blockIdx.y);
    else if (blockIdx.z == 1)
        gemm_body<1>(xb, wkb, bk, k,  blockIdx.x, blockIdx.y);
    else
        gemm_body<2>(xb, wvb, bv, vt, blockIdx.x, blockIdx.y);
}

// Kernel 4: output projection, fp32 out
__global__ __launch_bounds__(256) void out_gemm(
    const unsigned short* __restrict__ attn, const unsigned short* __restrict__ wob,
    const float* __restrict__ bo, float* __restrict__ out)
{
    gemm_body<0>(attn, wob, bo, out, blockIdx.x, blockIdx.y);
}

// ---------------------------------------------------------------------------
// Kernel 3: flash attention, reduction-free softmax, double-buffered staging.
// 4 waves, 64 Q-rows/block (16/wave), KV tiles of 64, grid (bh=32, qt=32).
// bh is the FAST grid index -> linear bid % 8 == bh % 8 -> all 32 qt-blocks
// of one (b,h) land on the same XCD; K+V (512 KB/bh) stays L2-resident.
// One barrier per iter: after the barrier opens compute on buf[cur], waves
// immediately issue async loads for tile i+1 into buf[cur^1]; the loads have
// the whole compute phase to land before the next barrier's vmcnt drain.
// Scores pre-scaled by 1/sqrt(DH)*log2e (folded into Q projection); no
// running max; row-sum l via MFMA against a constant bf16-ones B-frag.
// P: C-layout -> pair-shfl pack -> bf16 LDS (stride 72) -> A-layout b128.
// ---------------------------------------------------------------------------
__global__ __launch_bounds__(256) void attn_kernel(
    const unsigned short* __restrict__ q, const unsigned short* __restrict__ k,
    const unsigned short* __restrict__ vt, unsigned short* __restrict__ o)
{
    __shared__ __align__(16) unsigned short Ks[2][64 * 64];   // 16 KB dbuf [kv][dh]
    __shared__ __align__(16) unsigned short Vs[2][64 * 64];   // 16 KB dbuf [dh][kv]
    __shared__ __align__(16) unsigned short Ps[4][16 * 72];   //  9 KB per-wave P

    const int tid = threadIdx.x;
    const int lane = tid & 63, wave = tid >> 6;
    const int l15 = lane & 15, quad = lane >> 4;
    const int bh = blockIdx.x;        // b*H + h (0..31)  — FAST index: XCD = bh%8
    const int qt = blockIdx.y;        // Q tile (0..31)
    const int b = bh >> 4, h = bh & 15;

    const unsigned short* qb = q  + (size_t)b * N_ * D_ + h * DH_;
    const unsigned short* kb = k  + (size_t)b * N_ * D_ + h * DH_;
    const unsigned short* vb = vt + (size_t)h * DH_ * BN_ + (size_t)b * N_;  // vt[h*64+dh][b*N+n]

    const int qrow0 = qt * 64 + wave * 16;

    // Q fragments (A-layout, pre-scaled), resident for the whole KV loop
    short8 qf[2];
#pragma unroll
    for (int kf = 0; kf < 2; kf++)
        qf[kf] = *(const short8*)(qb + (size_t)(qrow0 + l15) * D_ + kf * 32 + quad * 8);

    f32x4 oacc[4] = {};
    f32x4 lacc = {};

    // constant bf16 ones B-frag for the row-sum MFMA
    short8 onesf;
#pragma unroll
    for (int j = 0; j < 8; j++) onesf[j] = (short)0x3F80;

    unsigned short* Pw = (unsigned short*)Ps[wave];
    const int srow = lane >> 3, scb = lane & 7;
    const bool even = (l15 & 1) == 0;
    const int cbase = even ? l15 : (15 + l15);

    // stage K/V tile kv0 into buffer bi (2 async chunks each per wave)
    auto stage = [&](int bi, int kv0) {
#pragma unroll
        for (int cc = 0; cc < 2; ++cc) {
            int c  = wave * 2 + cc;
            int lr = c * 8 + srow;             // 0..63
            int swz8 = (scb ^ (lr & 7)) * 8;
            async_load16(kb + (size_t)(kv0 + lr) * D_ + swz8, (unsigned short*)Ks[bi] + c * 512);
            async_load16(vb + (size_t)lr * BN_ + kv0 + swz8,  (unsigned short*)Vs[bi] + c * 512);
        }
    };

    stage(0, 0);   // prologue: fill buffer 0

    const int NIT = N_ / 64;   // 32
    for (int it = 0; it < NIT; ++it) {
        const int cur = it & 1;
        __syncthreads();   // drains vmcnt -> buf[cur] ready; buf[cur^1] free to overwrite
        if (it + 1 < NIT) stage(cur ^ 1, (it + 1) * 64);   // prefetch next tile

        const unsigned short* Kc = Ks[cur];
        const unsigned short* Vc = Vs[cur];

        // S = Q K^T  (4 n-blocks, scores already in log2 domain)
        f32x4 s[4] = {};
#pragma unroll
        for (int kf = 0; kf < 2; kf++) {
            const int swz = ((kf * 4 + quad) ^ (l15 & 7)) * 8;
            short8 kfr[4];
#pragma unroll
            for (int nb = 0; nb < 4; nb++)
                kfr[nb] = *(const short8*)(&Kc[(nb * 16 + l15) * 64 + swz]);
#pragma unroll
            for (int nb = 0; nb < 4; nb++)
                s[nb] = __builtin_amdgcn_mfma_f32_16x16x32_bf16(
                    qf[kf], kfr[nb], s[nb], 0, 0, 0);
        }

        // p = exp2(s); pack col pairs via xor-1 exchange -> 2 b32 LDS writes
#pragma unroll
        for (int r = 0; r < 4; r++) {
            float p0 = exp2f(s[0][r]);
            float p1 = exp2f(s[1][r]);
            float p2 = exp2f(s[2][r]);
            float p3 = exp2f(s[3][r]);
            float t0 = __shfl_xor(p0, 1);
            float t1 = __shfl_xor(p1, 1);
            float t2 = __shfl_xor(p2, 1);
            float t3 = __shfl_xor(p3, 1);
            // even lane: cols (l15,l15+1) of nb{0,2}; odd: cols 16+(l15-1,l15) of nb{1,3}
            unsigned int d0 = even ? pkbf(p0, t0) : pkbf(t1, p1);
            unsigned int d1 = even ? pkbf(p2, t2) : pkbf(t3, p3);
            int prow = quad * 4 + r;
            *(unsigned int*)(&Pw[prow * 72 + cbase])      = d0;
            *(unsigned int*)(&Pw[prow * 72 + cbase + 32]) = d1;
        }

        // PV: O += P V, l += P 1  (wave-local P; compiler orders DS ops)
#pragma unroll
        for (int kf = 0; kf < 2; kf++) {
            short8 pf = *(const short8*)(&Pw[l15 * 72 + kf * 32 + quad * 8]);
            const int swz = ((kf * 4 + quad) ^ (l15 & 7)) * 8;
#pragma unroll
            for (int db = 0; db < 4; db++) {
                short8 vf = *(const short8*)(&Vc[(db * 16 + l15) * 64 + swz]);
                oacc[db] = __builtin_amdgcn_mfma_f32_16x16x32_bf16(pf, vf, oacc[db], 0, 0, 0);
            }
            lacc = __builtin_amdgcn_mfma_f32_16x16x32_bf16(pf, onesf, lacc, 0, 0, 0);
        }
    }

    // epilogue: normalize by l, store bf16 attention output [B*N][D]
#pragma unroll
    for (int r = 0; r < 4; r++) {
        float inv = 1.f / lacc[r];
        int row = qrow0 + quad * 4 + r;
        size_t base = ((size_t)b * N_ + row) * D_ + h * DH_;
#pragma unroll
        for (int db = 0; db < 4; db++)
            o[base + db * 16 + l15] = f2bf(oacc[db][r] * inv);
    }
}

// ---------------------------------------------------------------------------
extern "C" void kernel_launch(void* const* d_in, const int* in_sizes, int n_in,
                              void* d_out, int out_size, void* d_ws, size_t ws_size,
                              hipStream_t stream)
{
    const float* x  = (const float*)d_in[0];
    const float* Wq = (const float*)d_in[1];
    const float* bq = (const float*)d_in[2];
    const float* Wk = (const float*)d_in[3];
    const float* bk = (const float*)d_in[4];
    const float* Wv = (const float*)d_in[5];
    const float* bv = (const float*)d_in[6];
    const float* Wo = (const float*)d_in[7];
    const float* bo = (const float*)d_in[8];
    float* out = (float*)d_out;

    char* ws = (char*)d_ws;
    unsigned short* xb  = (unsigned short*)(ws + 0);         //  8 MB  x bf16
    unsigned short* wqb = (unsigned short*)(ws + 8388608);   //  2 MB
    unsigned short* wkb = (unsigned short*)(ws + 10485760);  //  2 MB
    unsigned short* wvb = (unsigned short*)(ws + 12582912);  //  2 MB
    unsigned short* wob = (unsigned short*)(ws + 14680064);  //  2 MB
    unsigned short* qd  = (unsigned short*)(ws + 16777216);  //  8 MB  Q (pre-scaled)
    unsigned short* kd  = (unsigned short*)(ws + 25165824);  //  8 MB
    unsigned short* vtd = (unsigned short*)(ws + 33554432);  //  8 MB  V^T [D][B*N]
    unsigned short* ad  = (unsigned short*)(ws + 41943040);  //  8 MB  attn out
    // total 48 MB

    cast_kernel<<<8192, 256, 0, stream>>>(x, Wq, Wk, Wv, Wo, xb, wqb, wkb, wvb, wob);
    qkv_gemm<<<dim3(8, 32, 3), 256, 0, stream>>>(xb, wqb, wkb, wvb, bq, bk, bv, qd, kd, vtd);
    attn_kernel<<<dim3(32, 32), 256, 0, stream>>>(qd, kd, vtd, ad);
    out_gemm<<<dim3(8, 32), 256, 0, stream>>>(ad, wob, bo, out);
}

// Round 7
// 226.282 us; speedup vs baseline: 1.2011x; 1.2011x over previous
//
#include <hip/hip_runtime.h>
#include <hip/hip_bf16.h>

// Problem constants
#define B_  2
#define N_  2048
#define D_  1024
#define H_  16
#define DH_ 64
#define BN_ (B_*N_)   // 4096 rows total

typedef __attribute__((ext_vector_type(8))) short short8;    // 8 bf16 (MFMA A/B frag)
typedef __attribute__((ext_vector_type(4))) short short4v;   // 4 bf16 (8B, same TBAA as short8)
typedef __attribute__((ext_vector_type(4))) float f32x4;     // 16x16 C/D frag
typedef __attribute__((ext_vector_type(16))) float f32x16;   // 32x32 C/D frag

typedef __attribute__((address_space(3))) unsigned int lds_u32_t;
typedef const __attribute__((address_space(1))) unsigned int glb_u32_t;

// async global->LDS, 16B per lane; LDS dst = (wave-uniform base) + lane*16
__device__ __forceinline__ void async_load16(const unsigned short* g, unsigned short* l) {
    __builtin_amdgcn_global_load_lds((glb_u32_t*)g, (lds_u32_t*)l, 16, 0, 0);
}

__device__ __forceinline__ unsigned short f2bf(float f) {
    __hip_bfloat16 h = __float2bfloat16(f);
    return *reinterpret_cast<unsigned short*>(&h);
}

// pack bf16(a) low16 | bf16(b) high16; round-half-up + one v_perm_b32
__device__ __forceinline__ unsigned int pkbf(float a, float b) {
    unsigned int ua = __float_as_uint(a) + 0x8000u;
    unsigned int ub = __float_as_uint(b) + 0x8000u;
    return __builtin_amdgcn_perm(ub, ua, 0x07060302);
}

#if __has_builtin(__builtin_amdgcn_exp2f)
#define EXP2(x) __builtin_amdgcn_exp2f(x)
#else
#define EXP2(x) exp2f(x)
#endif

// softmax scale folded into Q projection: 1/sqrt(DH) * log2(e)
#define QSCL 0.1803368801111204f

// ---------------------------------------------------------------------------
// Kernel 1: cast fp32 -> bf16 for x, Wq, Wk, Wv, Wo (one fused launch)
// ---------------------------------------------------------------------------
__global__ __launch_bounds__(256) void cast_kernel(
    const float* __restrict__ x,  const float* __restrict__ wq,
    const float* __restrict__ wk, const float* __restrict__ wv,
    const float* __restrict__ wo,
    unsigned short* __restrict__ xb,  unsigned short* __restrict__ wqb,
    unsigned short* __restrict__ wkb, unsigned short* __restrict__ wvb,
    unsigned short* __restrict__ wob)
{
    const size_t NX = (size_t)BN_ * D_;   // 4194304
    const size_t NW = (size_t)D_ * D_;    // 1048576 (pow2)
    size_t i = ((size_t)blockIdx.x * 256 + threadIdx.x) * 4;
    const float* src; unsigned short* dst; size_t off;
    if (i < NX) { src = x; dst = xb; off = i; }
    else {
        size_t j = (i - NX) >> 20;          // which W
        off = (i - NX) & (NW - 1);
        src = (j == 0) ? wq : (j == 1) ? wk : (j == 2) ? wv : wo;
        dst = (j == 0) ? wqb : (j == 1) ? wkb : (j == 2) ? wvb : wob;
    }
    float4 v = *(const float4*)(src + off);
    ushort4 o;
    o.x = f2bf(v.x); o.y = f2bf(v.y); o.z = f2bf(v.z); o.w = f2bf(v.w);
    *(ushort4*)(dst + off) = o;
}

// ---------------------------------------------------------------------------
// GEMM body: C[M,Nc] = A[M,K](bf16) @ W[Nc,K]^T(bf16) + bias  (unchanged)
// ---------------------------------------------------------------------------
template<int OUT_MODE>
__device__ __forceinline__ void gemm_body(
    const unsigned short* __restrict__ A, const unsigned short* __restrict__ W,
    const float* __restrict__ bias, void* __restrict__ Cout, int bx, int by)
{
    constexpr int K = D_;
    __shared__ __align__(16) unsigned short As[128 * 64];   // 16 KB
    __shared__ __align__(16) unsigned short Bs[128 * 64];   // 16 KB
    const int tid  = threadIdx.x;
    const int lane = tid & 63;
    const int wave = tid >> 6;
    const int wm = wave & 1, wn = wave >> 1;
    const int l15 = lane & 15, quad = lane >> 4;

    f32x4 acc[4][4] = {};
    const int row0 = by * 128, col0 = bx * 128;

    const int srow = lane >> 3;   // row within 1KB chunk (8 rows x 128B)
    const int scb  = lane & 7;    // 16B block within row

    for (int k0 = 0; k0 < K; k0 += 64) {
        __syncthreads();
#pragma unroll
        for (int cc = 0; cc < 4; ++cc) {       // 16 chunks / 4 waves
            int c  = wave * 4 + cc;
            int lr = c * 8 + srow;             // tile row 0..127
            int gcol = k0 + ((scb ^ (lr & 7)) * 8);
            async_load16(A + (size_t)(row0 + lr) * K + gcol, (unsigned short*)As + c * 512);
            async_load16(W + (size_t)(col0 + lr) * K + gcol, (unsigned short*)Bs + c * 512);
        }
        __syncthreads();

#pragma unroll
        for (int kf = 0; kf < 2; ++kf) {
            const int swz = ((kf * 4 + quad) ^ (l15 & 7)) * 8;
            short8 af[4], bf[4];
#pragma unroll
            for (int mi = 0; mi < 4; mi++)
                af[mi] = *(const short8*)(&As[(wm * 64 + mi * 16 + l15) * 64 + swz]);
#pragma unroll
            for (int ni = 0; ni < 4; ni++)
                bf[ni] = *(const short8*)(&Bs[(wn * 64 + ni * 16 + l15) * 64 + swz]);
#pragma unroll
            for (int mi = 0; mi < 4; mi++)
#pragma unroll
                for (int ni = 0; ni < 4; ni++)
                    acc[mi][ni] = __builtin_amdgcn_mfma_f32_16x16x32_bf16(
                        af[mi], bf[ni], acc[mi][ni], 0, 0, 0);
        }
    }

#pragma unroll
    for (int ni = 0; ni < 4; ni++) {
        int col = col0 + wn * 64 + ni * 16 + l15;
        float bv = bias[col];
#pragma unroll
        for (int mi = 0; mi < 4; mi++) {
            int row = row0 + wm * 64 + mi * 16 + quad * 4;
            if (OUT_MODE == 2) {
                ushort4 pk;
                pk.x = f2bf(acc[mi][ni][0] + bv);
                pk.y = f2bf(acc[mi][ni][1] + bv);
                pk.z = f2bf(acc[mi][ni][2] + bv);
                pk.w = f2bf(acc[mi][ni][3] + bv);
                *(ushort4*)((unsigned short*)Cout + (size_t)col * BN_ + row) = pk;
            } else {
#pragma unroll
                for (int r = 0; r < 4; r++) {
                    float v = acc[mi][ni][r] + bv;
                    if (OUT_MODE == 3) v *= QSCL;
                    if (OUT_MODE == 0)
                        ((float*)Cout)[(size_t)(row + r) * D_ + col] = v;
                    else
                        ((unsigned short*)Cout)[(size_t)(row + r) * D_ + col] = f2bf(v);
                }
            }
        }
    }
}

// Kernel 2: fused QKV projection (z selects q/k/v; q pre-scaled, v transposed)
__global__ __launch_bounds__(256) void qkv_gemm(
    const unsigned short* __restrict__ xb,
    const unsigned short* __restrict__ wqb, const unsigned short* __restrict__ wkb,
    const unsigned short* __restrict__ wvb,
    const float* __restrict__ bq, const float* __restrict__ bk, const float* __restrict__ bv,
    unsigned short* __restrict__ q, unsigned short* __restrict__ k, unsigned short* __restrict__ vt)
{
    if (blockIdx.z == 0)
        gemm_body<3>(xb, wqb, bq, q,  blockIdx.x, blockIdx.y);
    else if (blockIdx.z == 1)
        gemm_body<1>(xb, wkb, bk, k,  blockIdx.x, blockIdx.y);
    else
        gemm_body<2>(xb, wvb, bv, vt, blockIdx.x, blockIdx.y);
}

// Kernel 4: output projection, fp32 out
__global__ __launch_bounds__(256) void out_gemm(
    const unsigned short* __restrict__ attn, const unsigned short* __restrict__ wob,
    const float* __restrict__ bo, float* __restrict__ out)
{
    gemm_body<0>(attn, wob, bo, out, blockIdx.x, blockIdx.y);
}

// ---------------------------------------------------------------------------
// Kernel 3: flash attention on 32x32x16 MFMA, S^T trick, no shfl.
// Same structure as R6, with the P write->read race closed:
//  (a) P stores go through short-element vector types (same TBAA family as
//      the short8 reads -> compiler cannot assume no-alias),
//  (b) explicit s_waitcnt lgkmcnt(0) + compiler memory barrier between the
//      P-write phase and the PV-read phase (HW drain, no reordering).
// Anti-dep (PV reads iter i vs P writes iter i+1) is covered by the loop-top
// __syncthreads' lgkm drain.
// ---------------------------------------------------------------------------
__global__ __launch_bounds__(256) void attn_kernel(
    const unsigned short* __restrict__ q, const unsigned short* __restrict__ k,
    const unsigned short* __restrict__ vt, unsigned short* __restrict__ o)
{
    __shared__ __align__(16) unsigned short Ks[64 * 64];      //  8 KB [kv][dh] swizzled
    __shared__ __align__(16) unsigned short Vs[64 * 64];      //  8 KB [dh][kv] swizzled
    __shared__ __align__(16) unsigned short Ps[4][32 * 72];   // 18 KB per-wave P [qrow][kv]

    const int tid = threadIdx.x;
    const int lane = tid & 63, wave = tid >> 6;
    const int l31 = lane & 31, kq = lane >> 5;     // kq: which K-half of the frag
    const int bh = blockIdx.x;        // b*H + h (0..31) — FAST index: XCD = bh%8
    const int qt = blockIdx.y;        // Q tile (0..15)
    const int b = bh >> 4, h = bh & 15;

    const unsigned short* qb = q  + (size_t)b * N_ * D_ + h * DH_;
    const unsigned short* kb = k  + (size_t)b * N_ * D_ + h * DH_;
    const unsigned short* vb = vt + (size_t)h * DH_ * BN_ + (size_t)b * N_;  // vt[h*64+dh][b*N+n]

    const int qrow0 = qt * 128 + wave * 32;

    // Q B-frags (pre-scaled): lane l31 holds Q[qrow0+l31][s*16 + kq*8 .. +7]
    short8 qf[4];
#pragma unroll
    for (int s = 0; s < 4; s++)
        qf[s] = *(const short8*)(qb + (size_t)(qrow0 + l31) * D_ + s * 16 + kq * 8);

    f32x16 oacc[2] = {};   // O[qrow][dh], nb = dh-half
    f32x16 lacc = {};      // row-sums (all cols identical)

    short8 onesf;
#pragma unroll
    for (int j = 0; j < 8; j++) onesf[j] = (short)0x3F80;

    char* Pw = (char*)Ps[wave];
    const int pswz = (l31 >> 3) & 3;          // P swizzle (16B-block units)
    const int srow = lane >> 3, scb = lane & 7;

    for (int kv0 = 0; kv0 < N_; kv0 += 64) {
        __syncthreads();   // previous iteration's Ks/Vs readers done (drains lgkm+vm)
#pragma unroll
        for (int cc = 0; cc < 2; ++cc) {       // 8 chunks / 4 waves, K and V
            int c  = wave * 2 + cc;
            int lr = c * 8 + srow;             // 0..63
            int swz8 = (scb ^ (lr & 7)) * 8;
            async_load16(kb + (size_t)(kv0 + lr) * D_ + swz8, (unsigned short*)Ks + c * 512);
            async_load16(vb + (size_t)lr * BN_ + kv0 + swz8,  (unsigned short*)Vs + c * 512);
        }
        __syncthreads();   // staging complete

        // S^T = K·Q^T  (2 kv-halves x 4 dh-steps)
        f32x16 st[2] = {};
#pragma unroll
        for (int s = 0; s < 4; s++) {
#pragma unroll
            for (int mb = 0; mb < 2; mb++) {
                short8 kfr = *(const short8*)((const char*)Ks +
                    (mb * 32 + l31) * 128 + (((2 * s + kq) ^ (l31 & 7)) * 16));
                st[mb] = __builtin_amdgcn_mfma_f32_32x32x16_bf16(
                    kfr, qf[s], st[mb], 0, 0, 0);
            }
        }

        // p = exp2(s^T); pack 4 consecutive KV per reg-quad -> b64 LDS writes
#pragma unroll
        for (int mb = 0; mb < 2; mb++) {
#pragma unroll
            for (int g = 0; g < 4; g++) {
                float p0 = EXP2(st[mb][g * 4 + 0]);
                float p1 = EXP2(st[mb][g * 4 + 1]);
                float p2 = EXP2(st[mb][g * 4 + 2]);
                float p3 = EXP2(st[mb][g * 4 + 3]);
                uint2 val;
                val.x = pkbf(p0, p1);
                val.y = pkbf(p2, p3);
                // kv = mb*32 + g*8 + kq*4 + rr  -> 8B-block ib = mb*8+g*2+kq
                int ib = (mb * 8 + g * 2 + kq) ^ (pswz * 2);
                *(short4v*)(Pw + l31 * 144 + ib * 8) = __builtin_bit_cast(short4v, val);
            }
        }

        // HW drain + compiler fence: all P ds_writes complete before any PV read
        asm volatile("s_waitcnt lgkmcnt(0)" ::: "memory");

        // PV: O += P·V, l += P·1  (wave-local P)
#pragma unroll
        for (int s = 0; s < 4; s++) {
            short8 pf = *(const short8*)(Pw + l31 * 144 + (((2 * s + kq) ^ pswz) * 16));
#pragma unroll
            for (int nb = 0; nb < 2; nb++) {
                short8 vf = *(const short8*)((const char*)Vs +
                    (nb * 32 + l31) * 128 + (((2 * s + kq) ^ (l31 & 7)) * 16));
                oacc[nb] = __builtin_amdgcn_mfma_f32_32x32x16_bf16(pf, vf, oacc[nb], 0, 0, 0);
            }
            lacc = __builtin_amdgcn_mfma_f32_32x32x16_bf16(pf, onesf, lacc, 0, 0, 0);
        }
    }

    // epilogue: normalize by l, store bf16 attention output [B*N][D]
#pragma unroll
    for (int g = 0; g < 4; g++)
#pragma unroll
        for (int rr = 0; rr < 4; rr++) {
            int reg = g * 4 + rr;
            float inv = 1.f / lacc[reg];
            int row = qrow0 + rr + 8 * g + 4 * kq;
            size_t base = ((size_t)b * N_ + row) * D_ + h * DH_;
#pragma unroll
            for (int nb = 0; nb < 2; nb++)
                o[base + nb * 32 + l31] = f2bf(oacc[nb][reg] * inv);
        }
}

// ---------------------------------------------------------------------------
extern "C" void kernel_launch(void* const* d_in, const int* in_sizes, int n_in,
                              void* d_out, int out_size, void* d_ws, size_t ws_size,
                              hipStream_t stream)
{
    const float* x  = (const float*)d_in[0];
    const float* Wq = (const float*)d_in[1];
    const float* bq = (const float*)d_in[2];
    const float* Wk = (const float*)d_in[3];
    const float* bk = (const float*)d_in[4];
    const float* Wv = (const float*)d_in[5];
    const float* bv = (const float*)d_in[6];
    const float* Wo = (const float*)d_in[7];
    const float* bo = (const float*)d_in[8];
    float* out = (float*)d_out;

    char* ws = (char*)d_ws;
    unsigned short* xb  = (unsigned short*)(ws + 0);         //  8 MB  x bf16
    unsigned short* wqb = (unsigned short*)(ws + 8388608);   //  2 MB
    unsigned short* wkb = (unsigned short*)(ws + 10485760);  //  2 MB
    unsigned short* wvb = (unsigned short*)(ws + 12582912);  //  2 MB
    unsigned short* wob = (unsigned short*)(ws + 14680064);  //  2 MB
    unsigned short* qd  = (unsigned short*)(ws + 16777216);  //  8 MB  Q (pre-scaled)
    unsigned short* kd  = (unsigned short*)(ws + 25165824);  //  8 MB
    unsigned short* vtd = (unsigned short*)(ws + 33554432);  //  8 MB  V^T [D][B*N]
    unsigned short* ad  = (unsigned short*)(ws + 41943040);  //  8 MB  attn out
    // total 48 MB

    cast_kernel<<<8192, 256, 0, stream>>>(x, Wq, Wk, Wv, Wo, xb, wqb, wkb, wvb, wob);
    qkv_gemm<<<dim3(8, 32, 3), 256, 0, stream>>>(xb, wqb, wkb, wvb, bq, bk, bv, qd, kd, vtd);
    attn_kernel<<<dim3(32, 16), 256, 0, stream>>>(qd, kd, vtd, ad);
    out_gemm<<<dim3(8, 32), 256, 0, stream>>>(ad, wob, bo, out);
}

// Round 8
// 210.406 us; speedup vs baseline: 1.2917x; 1.0755x over previous
//
#include <hip/hip_runtime.h>
#include <hip/hip_bf16.h>

// Problem constants
#define B_  2
#define N_  2048
#define D_  1024
#define H_  16
#define DH_ 64
#define BN_ (B_*N_)   // 4096 rows total

typedef __attribute__((ext_vector_type(8))) short short8;    // 8 bf16 (MFMA A/B frag)
typedef __attribute__((ext_vector_type(4))) short short4v;   // 4 bf16 (8B, same TBAA as short8)
typedef __attribute__((ext_vector_type(4))) float f32x4;     // 16x16 C/D frag
typedef __attribute__((ext_vector_type(16))) float f32x16;   // 32x32 C/D frag

typedef __attribute__((address_space(3))) unsigned int lds_u32_t;
typedef const __attribute__((address_space(1))) unsigned int glb_u32_t;

// async global->LDS, 16B per lane; LDS dst = (wave-uniform base) + lane*16
__device__ __forceinline__ void async_load16(const unsigned short* g, unsigned short* l) {
    __builtin_amdgcn_global_load_lds((glb_u32_t*)g, (lds_u32_t*)l, 16, 0, 0);
}

__device__ __forceinline__ unsigned short f2bf(float f) {
    __hip_bfloat16 h = __float2bfloat16(f);
    return *reinterpret_cast<unsigned short*>(&h);
}

// pack bf16(a) low16 | bf16(b) high16; round-half-up + one v_perm_b32
__device__ __forceinline__ unsigned int pkbf(float a, float b) {
    unsigned int ua = __float_as_uint(a) + 0x8000u;
    unsigned int ub = __float_as_uint(b) + 0x8000u;
    return __builtin_amdgcn_perm(ub, ua, 0x07060302);
}

#if __has_builtin(__builtin_amdgcn_exp2f)
#define EXP2(x) __builtin_amdgcn_exp2f(x)
#else
#define EXP2(x) exp2f(x)
#endif

// softmax scale folded into Q projection: 1/sqrt(DH) * log2(e)
#define QSCL 0.1803368801111204f

// ---------------------------------------------------------------------------
// Kernel 1: cast fp32 -> bf16 for x, Wq, Wk, Wv, Wo (one fused launch)
// ---------------------------------------------------------------------------
__global__ __launch_bounds__(256) void cast_kernel(
    const float* __restrict__ x,  const float* __restrict__ wq,
    const float* __restrict__ wk, const float* __restrict__ wv,
    const float* __restrict__ wo,
    unsigned short* __restrict__ xb,  unsigned short* __restrict__ wqb,
    unsigned short* __restrict__ wkb, unsigned short* __restrict__ wvb,
    unsigned short* __restrict__ wob)
{
    const size_t NX = (size_t)BN_ * D_;   // 4194304
    const size_t NW = (size_t)D_ * D_;    // 1048576 (pow2)
    size_t i = ((size_t)blockIdx.x * 256 + threadIdx.x) * 4;
    const float* src; unsigned short* dst; size_t off;
    if (i < NX) { src = x; dst = xb; off = i; }
    else {
        size_t j = (i - NX) >> 20;          // which W
        off = (i - NX) & (NW - 1);
        src = (j == 0) ? wq : (j == 1) ? wk : (j == 2) ? wv : wo;
        dst = (j == 0) ? wqb : (j == 1) ? wkb : (j == 2) ? wvb : wob;
    }
    float4 v = *(const float4*)(src + off);
    ushort4 o;
    o.x = f2bf(v.x); o.y = f2bf(v.y); o.z = f2bf(v.z); o.w = f2bf(v.w);
    *(ushort4*)(dst + off) = o;
}

// ---------------------------------------------------------------------------
// GEMM body: C[M,Nc] = A[M,K](bf16) @ W[Nc,K]^T(bf16) + bias
// LDS buffers are passed in (declared ONCE at kernel scope) so multiple
// template instantiations in one kernel share the same 32 KB allocation
// (static __shared__ inside each instantiation tripled qkv_gemm's LDS to
// 96 KB -> 1 block/CU, Occupancy 10% — R7 counters).
// ---------------------------------------------------------------------------
template<int OUT_MODE>
__device__ __forceinline__ void gemm_body(
    unsigned short* __restrict__ As, unsigned short* __restrict__ Bs,
    const unsigned short* __restrict__ A, const unsigned short* __restrict__ W,
    const float* __restrict__ bias, void* __restrict__ Cout, int bx, int by)
{
    constexpr int K = D_;
    const int tid  = threadIdx.x;
    const int lane = tid & 63;
    const int wave = tid >> 6;
    const int wm = wave & 1, wn = wave >> 1;
    const int l15 = lane & 15, quad = lane >> 4;

    f32x4 acc[4][4] = {};
    const int row0 = by * 128, col0 = bx * 128;

    const int srow = lane >> 3;   // row within 1KB chunk (8 rows x 128B)
    const int scb  = lane & 7;    // 16B block within row

    for (int k0 = 0; k0 < K; k0 += 64) {
        __syncthreads();
#pragma unroll
        for (int cc = 0; cc < 4; ++cc) {       // 16 chunks / 4 waves
            int c  = wave * 4 + cc;
            int lr = c * 8 + srow;             // tile row 0..127
            int gcol = k0 + ((scb ^ (lr & 7)) * 8);
            async_load16(A + (size_t)(row0 + lr) * K + gcol, As + c * 512);
            async_load16(W + (size_t)(col0 + lr) * K + gcol, Bs + c * 512);
        }
        __syncthreads();

#pragma unroll
        for (int kf = 0; kf < 2; ++kf) {
            const int swz = ((kf * 4 + quad) ^ (l15 & 7)) * 8;
            short8 af[4], bf[4];
#pragma unroll
            for (int mi = 0; mi < 4; mi++)
                af[mi] = *(const short8*)(&As[(wm * 64 + mi * 16 + l15) * 64 + swz]);
#pragma unroll
            for (int ni = 0; ni < 4; ni++)
                bf[ni] = *(const short8*)(&Bs[(wn * 64 + ni * 16 + l15) * 64 + swz]);
#pragma unroll
            for (int mi = 0; mi < 4; mi++)
#pragma unroll
                for (int ni = 0; ni < 4; ni++)
                    acc[mi][ni] = __builtin_amdgcn_mfma_f32_16x16x32_bf16(
                        af[mi], bf[ni], acc[mi][ni], 0, 0, 0);
        }
    }

#pragma unroll
    for (int ni = 0; ni < 4; ni++) {
        int col = col0 + wn * 64 + ni * 16 + l15;
        float bv = bias[col];
#pragma unroll
        for (int mi = 0; mi < 4; mi++) {
            int row = row0 + wm * 64 + mi * 16 + quad * 4;
            if (OUT_MODE == 2) {
                ushort4 pk;
                pk.x = f2bf(acc[mi][ni][0] + bv);
                pk.y = f2bf(acc[mi][ni][1] + bv);
                pk.z = f2bf(acc[mi][ni][2] + bv);
                pk.w = f2bf(acc[mi][ni][3] + bv);
                *(ushort4*)((unsigned short*)Cout + (size_t)col * BN_ + row) = pk;
            } else {
#pragma unroll
                for (int r = 0; r < 4; r++) {
                    float v = acc[mi][ni][r] + bv;
                    if (OUT_MODE == 3) v *= QSCL;
                    if (OUT_MODE == 0)
                        ((float*)Cout)[(size_t)(row + r) * D_ + col] = v;
                    else
                        ((unsigned short*)Cout)[(size_t)(row + r) * D_ + col] = f2bf(v);
                }
            }
        }
    }
}

// Kernel 2: fused QKV projection (z selects q/k/v; q pre-scaled, v transposed)
__global__ __launch_bounds__(256) void qkv_gemm(
    const unsigned short* __restrict__ xb,
    const unsigned short* __restrict__ wqb, const unsigned short* __restrict__ wkb,
    const unsigned short* __restrict__ wvb,
    const float* __restrict__ bq, const float* __restrict__ bk, const float* __restrict__ bv,
    unsigned short* __restrict__ q, unsigned short* __restrict__ k, unsigned short* __restrict__ vt)
{
    __shared__ __align__(16) unsigned short As[128 * 64];   // 16 KB — shared by all
    __shared__ __align__(16) unsigned short Bs[128 * 64];   // 16 KB   three branches
    if (blockIdx.z == 0)
        gemm_body<3>(As, Bs, xb, wqb, bq, q,  blockIdx.x, blockIdx.y);
    else if (blockIdx.z == 1)
        gemm_body<1>(As, Bs, xb, wkb, bk, k,  blockIdx.x, blockIdx.y);
    else
        gemm_body<2>(As, Bs, xb, wvb, bv, vt, blockIdx.x, blockIdx.y);
}

// Kernel 4: output projection, fp32 out
__global__ __launch_bounds__(256) void out_gemm(
    const unsigned short* __restrict__ attn, const unsigned short* __restrict__ wob,
    const float* __restrict__ bo, float* __restrict__ out)
{
    __shared__ __align__(16) unsigned short As[128 * 64];
    __shared__ __align__(16) unsigned short Bs[128 * 64];
    gemm_body<0>(As, Bs, attn, wob, bo, out, blockIdx.x, blockIdx.y);
}

// ---------------------------------------------------------------------------
// Kernel 3: flash attention on 32x32x16 MFMA, S^T trick, no shfl. (R7, passing)
// ---------------------------------------------------------------------------
__global__ __launch_bounds__(256) void attn_kernel(
    const unsigned short* __restrict__ q, const unsigned short* __restrict__ k,
    const unsigned short* __restrict__ vt, unsigned short* __restrict__ o)
{
    __shared__ __align__(16) unsigned short Ks[64 * 64];      //  8 KB [kv][dh] swizzled
    __shared__ __align__(16) unsigned short Vs[64 * 64];      //  8 KB [dh][kv] swizzled
    __shared__ __align__(16) unsigned short Ps[4][32 * 72];   // 18 KB per-wave P [qrow][kv]

    const int tid = threadIdx.x;
    const int lane = tid & 63, wave = tid >> 6;
    const int l31 = lane & 31, kq = lane >> 5;     // kq: which K-half of the frag
    const int bh = blockIdx.x;        // b*H + h (0..31) — FAST index: XCD = bh%8
    const int qt = blockIdx.y;        // Q tile (0..15)
    const int b = bh >> 4, h = bh & 15;

    const unsigned short* qb = q  + (size_t)b * N_ * D_ + h * DH_;
    const unsigned short* kb = k  + (size_t)b * N_ * D_ + h * DH_;
    const unsigned short* vb = vt + (size_t)h * DH_ * BN_ + (size_t)b * N_;  // vt[h*64+dh][b*N+n]

    const int qrow0 = qt * 128 + wave * 32;

    // Q B-frags (pre-scaled): lane l31 holds Q[qrow0+l31][s*16 + kq*8 .. +7]
    short8 qf[4];
#pragma unroll
    for (int s = 0; s < 4; s++)
        qf[s] = *(const short8*)(qb + (size_t)(qrow0 + l31) * D_ + s * 16 + kq * 8);

    f32x16 oacc[2] = {};   // O[qrow][dh], nb = dh-half
    f32x16 lacc = {};      // row-sums (all cols identical)

    short8 onesf;
#pragma unroll
    for (int j = 0; j < 8; j++) onesf[j] = (short)0x3F80;

    char* Pw = (char*)Ps[wave];
    const int pswz = (l31 >> 3) & 3;          // P swizzle (16B-block units)
    const int srow = lane >> 3, scb = lane & 7;

    for (int kv0 = 0; kv0 < N_; kv0 += 64) {
        __syncthreads();   // previous iteration's Ks/Vs readers done (drains lgkm+vm)
#pragma unroll
        for (int cc = 0; cc < 2; ++cc) {       // 8 chunks / 4 waves, K and V
            int c  = wave * 2 + cc;
            int lr = c * 8 + srow;             // 0..63
            int swz8 = (scb ^ (lr & 7)) * 8;
            async_load16(kb + (size_t)(kv0 + lr) * D_ + swz8, (unsigned short*)Ks + c * 512);
            async_load16(vb + (size_t)lr * BN_ + kv0 + swz8,  (unsigned short*)Vs + c * 512);
        }
        __syncthreads();   // staging complete

        // S^T = K·Q^T  (2 kv-halves x 4 dh-steps)
        f32x16 st[2] = {};
#pragma unroll
        for (int s = 0; s < 4; s++) {
#pragma unroll
            for (int mb = 0; mb < 2; mb++) {
                short8 kfr = *(const short8*)((const char*)Ks +
                    (mb * 32 + l31) * 128 + (((2 * s + kq) ^ (l31 & 7)) * 16));
                st[mb] = __builtin_amdgcn_mfma_f32_32x32x16_bf16(
                    kfr, qf[s], st[mb], 0, 0, 0);
            }
        }

        // p = exp2(s^T); pack 4 consecutive KV per reg-quad -> b64 LDS writes
#pragma unroll
        for (int mb = 0; mb < 2; mb++) {
#pragma unroll
            for (int g = 0; g < 4; g++) {
                float p0 = EXP2(st[mb][g * 4 + 0]);
                float p1 = EXP2(st[mb][g * 4 + 1]);
                float p2 = EXP2(st[mb][g * 4 + 2]);
                float p3 = EXP2(st[mb][g * 4 + 3]);
                uint2 val;
                val.x = pkbf(p0, p1);
                val.y = pkbf(p2, p3);
                // kv = mb*32 + g*8 + kq*4 + rr  -> 8B-block ib = mb*8+g*2+kq
                int ib = (mb * 8 + g * 2 + kq) ^ (pswz * 2);
                *(short4v*)(Pw + l31 * 144 + ib * 8) = __builtin_bit_cast(short4v, val);
            }
        }

        // HW drain + compiler fence: all P ds_writes complete before any PV read
        asm volatile("s_waitcnt lgkmcnt(0)" ::: "memory");

        // PV: O += P·V, l += P·1  (wave-local P)
#pragma unroll
        for (int s = 0; s < 4; s++) {
            short8 pf = *(const short8*)(Pw + l31 * 144 + (((2 * s + kq) ^ pswz) * 16));
#pragma unroll
            for (int nb = 0; nb < 2; nb++) {
                short8 vf = *(const short8*)((const char*)Vs +
                    (nb * 32 + l31) * 128 + (((2 * s + kq) ^ (l31 & 7)) * 16));
                oacc[nb] = __builtin_amdgcn_mfma_f32_32x32x16_bf16(pf, vf, oacc[nb], 0, 0, 0);
            }
            lacc = __builtin_amdgcn_mfma_f32_32x32x16_bf16(pf, onesf, lacc, 0, 0, 0);
        }
    }

    // epilogue: normalize by l, store bf16 attention output [B*N][D]
#pragma unroll
    for (int g = 0; g < 4; g++)
#pragma unroll
        for (int rr = 0; rr < 4; rr++) {
            int reg = g * 4 + rr;
            float inv = 1.f / lacc[reg];
            int row = qrow0 + rr + 8 * g + 4 * kq;
            size_t base = ((size_t)b * N_ + row) * D_ + h * DH_;
#pragma unroll
            for (int nb = 0; nb < 2; nb++)
                o[base + nb * 32 + l31] = f2bf(oacc[nb][reg] * inv);
        }
}

// ---------------------------------------------------------------------------
extern "C" void kernel_launch(void* const* d_in, const int* in_sizes, int n_in,
                              void* d_out, int out_size, void* d_ws, size_t ws_size,
                              hipStream_t stream)
{
    const float* x  = (const float*)d_in[0];
    const float* Wq = (const float*)d_in[1];
    const float* bq = (const float*)d_in[2];
    const float* Wk = (const float*)d_in[3];
    const float* bk = (const float*)d_in[4];
    const float* Wv = (const float*)d_in[5];
    const float* bv = (const float*)d_in[6];
    const float* Wo = (const float*)d_in[7];
    const float* bo = (const float*)d_in[8];
    float* out = (float*)d_out;

    char* ws = (char*)d_ws;
    unsigned short* xb  = (unsigned short*)(ws + 0);         //  8 MB  x bf16
    unsigned short* wqb = (unsigned short*)(ws + 8388608);   //  2 MB
    unsigned short* wkb = (unsigned short*)(ws + 10485760);  //  2 MB
    unsigned short* wvb = (unsigned short*)(ws + 12582912);  //  2 MB
    unsigned short* wob = (unsigned short*)(ws + 14680064);  //  2 MB
    unsigned short* qd  = (unsigned short*)(ws + 16777216);  //  8 MB  Q (pre-scaled)
    unsigned short* kd  = (unsigned short*)(ws + 25165824);  //  8 MB
    unsigned short* vtd = (unsigned short*)(ws + 33554432);  //  8 MB  V^T [D][B*N]
    unsigned short* ad  = (unsigned short*)(ws + 41943040);  //  8 MB  attn out
    // total 48 MB

    cast_kernel<<<8192, 256, 0, stream>>>(x, Wq, Wk, Wv, Wo, xb, wqb, wkb, wvb, wob);
    qkv_gemm<<<dim3(8, 32, 3), 256, 0, stream>>>(xb, wqb, wkb, wvb, bq, bk, bv, qd, kd, vtd);
    attn_kernel<<<dim3(32, 16), 256, 0, stream>>>(qd, kd, vtd, ad);
    out_gemm<<<dim3(8, 32), 256, 0, stream>>>(ad, wob, bo, out);
}